// Round 3
// baseline (1141.684 us; speedup 1.0000x reference)
//
#include <hip/hip_runtime.h>
#include <hip/hip_bf16.h>

// Problem constants
constexpr int BB = 2, FF = 8, CIN = 16, COUT = 32, HH = 128, WW = 128;
constexpr int HW = HH * WW;          // 16384
constexpr int NIMG = BB * FF;        // 16
constexpr int TAPS = 16;
constexpr int TILE = 32, HALO = 2, LT = TILE + 2 * HALO;  // 36
constexpr int LTSQ = LT * LT;        // 1296
constexpr int OCB = 16;              // output channels per block (z-split = 2)
constexpr int NSLOT = 256;           // 16 img * 16 tiles partial slots per channel

// Ring offsets in reference order, pre-biased: OFF[n] = (ox+2)*LT + (oy+2)
// OFF = {0,1,2,3,4, 40,76,112, 144,145,146,147,148, 36,72,108}; center = 2*36+2 = 74

__device__ __forceinline__ float leaky(float v) { return v >= 0.f ? v : 0.01f * v; }

template <int CI, bool PRE, bool XL>
__global__ __launch_bounds__(256)
void peak_conv(const float* __restrict__ in, const float* __restrict__ Wk,
               const float* __restrict__ bk, const float* __restrict__ prm,
               float* __restrict__ outp, float* __restrict__ P)
{
    __shared__ float tile[2][LTSQ];
    __shared__ float redS[4][OCB], redQ[4][OCB];

    const int tid    = threadIdx.x;
    const int tileid = blockIdx.x;        // 0..15  (4x4 tiles of 32x32)
    const int img    = blockIdx.y;        // 0..15
    const int ocb    = blockIdx.z * OCB;  // output-channel base
    const int tx     = (tileid & 3) * TILE;
    const int ty     = (tileid >> 2) * TILE;
    const int col    = tid & 31;
    const int row0   = tid >> 5;          // 0..7

    const int OFF[16] = {0,1,2,3,4, 40,76,112, 144,145,146,147,148, 36,72,108};

    // c-invariant staging geometry: 6 slots/thread cover 1296 tile elements
    int  soff[6];
    bool sval[6];
#pragma unroll
    for (int s = 0; s < 6; ++s) {
        int idx = s * 256 + tid;
        int r   = idx / LT, cc = idx - r * LT;
        int gh  = ty + r - HALO, gw = tx + cc - HALO;
        sval[s] = (idx < LTSQ) && ((unsigned)gh < (unsigned)HH) && ((unsigned)gw < (unsigned)WW);
        int ghc = min(max(gh, 0), HH - 1), gwc = min(max(gw, 0), WW - 1);
        soff[s] = ghc * WW + gwc;  // clamped => always safe to load
    }

    auto plane = [&](int c) -> const float* {
        if (XL) return in + (size_t)(((img >> 3) * CI + c) * FF + (img & 7)) * HW;
        else    return in + (size_t)(img * CI + c) * HW;
    };

    float acc[4][OCB];
#pragma unroll
    for (int k = 0; k < 4; ++k)
#pragma unroll
        for (int oo = 0; oo < OCB; ++oo) acc[k][oo] = 0.f;

    // prologue: load channel 0 into regs
    float g[6];
    {
        const float* s0 = plane(0);
#pragma unroll
        for (int s = 0; s < 6; ++s) { float t = s0[soff[s]]; g[s] = sval[s] ? t : 0.f; }
    }

    int cur = 0;
    for (int c = 0; c < CI; ++c) {
        // (1) transform + ds_write channel c into buf[cur]
        float pa = 0.f, pb = 0.f;
        if (PRE) { pa = prm[c]; pb = prm[COUT + c]; }
#pragma unroll
        for (int s = 0; s < 6; ++s) {
            float v = g[s];
            if (PRE) {
                float t = fmaf(pa, v, pb);
                t = leaky(t);
                v = sval[s] ? t : 0.f;   // padding is zero AFTER bn+leaky
            }
            int idx = s * 256 + tid;
            if (s < 5 || tid < (LTSQ - 5 * 256)) tile[cur][idx] = v;
        }
        // (2) issue next-channel global loads (latency hides under compute)
        if (c + 1 < CI) {
            const float* sn = plane(c + 1);
#pragma unroll
            for (int s = 0; s < 6; ++s) { float t = sn[soff[s]]; g[s] = sval[s] ? t : 0.f; }
        }
        // (3) one barrier per channel (dbuf makes this safe)
        __syncthreads();
        // (4) compute channel c
        const float* wbase = Wk + ((size_t)ocb * CI + c) * TAPS;
#pragma unroll
        for (int k = 0; k < 4; ++k) {
            const float* bp = &tile[cur][(row0 + 8 * k) * LT + col];
            float ctr = bp[74];
            float d[16];
#pragma unroll
            for (int n = 0; n < 16; ++n) d[n] = ctr - bp[OFF[n]];
#pragma unroll
            for (int n = 0; n < 16; ++n)
#pragma unroll
                for (int oo = 0; oo < OCB; ++oo)
                    acc[k][oo] = fmaf(wbase[(size_t)oo * CI * TAPS + n], d[n], acc[k][oo]);
        }
        cur ^= 1;
    }

    // epilogue: bias add, store, per-channel partial sums for BN stats
    const int slot = img * 16 + tileid;
    float ssum[OCB], ssq[OCB];
#pragma unroll
    for (int oo = 0; oo < OCB; ++oo) { ssum[oo] = 0.f; ssq[oo] = 0.f; }

#pragma unroll
    for (int k = 0; k < 4; ++k) {
        int gh = ty + row0 + 8 * k;
        int gw = tx + col;
#pragma unroll
        for (int oo = 0; oo < OCB; ++oo) {
            float v = acc[k][oo] + bk[ocb + oo];
            outp[(size_t)(img * COUT + ocb + oo) * HW + gh * WW + gw] = v;
            ssum[oo] += v;
            ssq[oo]  = fmaf(v, v, ssq[oo]);
        }
    }

    const int lane = tid & 63, wid = tid >> 6;
#pragma unroll
    for (int oo = 0; oo < OCB; ++oo) {
        float s = ssum[oo], q = ssq[oo];
#pragma unroll
        for (int m = 32; m >= 1; m >>= 1) {
            s += __shfl_xor(s, m);
            q += __shfl_xor(q, m);
        }
        if (lane == 0) { redS[wid][oo] = s; redQ[wid][oo] = q; }
    }
    __syncthreads();
    if (tid < OCB) {
        float s = redS[0][tid] + redS[1][tid] + redS[2][tid] + redS[3][tid];
        P[(size_t)(ocb + tid) * NSLOT + slot] = s;
    } else if (tid < 2 * OCB) {
        int oo = tid - OCB;
        float q = redQ[0][oo] + redQ[1][oo] + redQ[2][oo] + redQ[3][oo];
        P[(size_t)COUT * NSLOT + (size_t)(ocb + oo) * NSLOT + slot] = q;
    }
}

// One block per channel: reduce 256 partial sums/sumsq -> affine params a,b
__global__ __launch_bounds__(256)
void bn_stats(const float* __restrict__ P, const float* __restrict__ gamma,
              const float* __restrict__ beta, float* __restrict__ prm)
{
    __shared__ float rs[256], rq[256];
    const int c = blockIdx.x, tid = threadIdx.x;
    rs[tid] = P[(size_t)c * NSLOT + tid];
    rq[tid] = P[(size_t)COUT * NSLOT + (size_t)c * NSLOT + tid];
    __syncthreads();
    for (int s = 128; s > 0; s >>= 1) {
        if (tid < s) { rs[tid] += rs[tid + s]; rq[tid] += rq[tid + s]; }
        __syncthreads();
    }
    if (tid == 0) {
        const float n  = (float)(NIMG * HW);   // 262144
        float mu  = rs[0] / n;
        float var = rq[0] / n - mu * mu;
        float a   = gamma[c] * rsqrtf(var + 1e-5f);
        prm[c]        = a;
        prm[COUT + c] = beta[c] - mu * a;
    }
}

// BN2 + leaky + "mean over F" with the reference's FLAT-RESHAPE semantics:
//   out[b][o][p] = (1/8) sum_f leaky(bn2( t2[ img=b*8+(o>>2) ][ c=(o&3)*8+f ][p] ))
__global__ __launch_bounds__(256)
void finalize(const float* __restrict__ t2, const float* __restrict__ prm,
              float* __restrict__ outp)
{
    int gid = blockIdx.x * 256 + threadIdx.x;   // < B*COUT*HW = 1048576
    int p    = gid & (HW - 1);
    int rest = gid >> 14;
    int o    = rest & 31;
    int b    = rest >> 5;
    int img  = b * 8 + (o >> 2);
    int cb   = (o & 3) * 8;
    float s  = 0.f;
#pragma unroll
    for (int f = 0; f < FF; ++f) {
        int c   = cb + f;
        float a = prm[c], bb = prm[COUT + c];
        float v = t2[(size_t)(img * COUT + c) * HW + p];
        v = fmaf(a, v, bb);
        s += (v >= 0.f) ? v : 0.01f * v;
    }
    outp[gid] = 0.125f * s;
}

extern "C" void kernel_launch(void* const* d_in, const int* in_sizes, int n_in,
                              void* d_out, int out_size, void* d_ws, size_t ws_size,
                              hipStream_t stream)
{
    const float* x   = (const float*)d_in[0];
    const float* W1  = (const float*)d_in[1];
    const float* b1  = (const float*)d_in[2];
    const float* g1  = (const float*)d_in[3];
    const float* be1 = (const float*)d_in[4];
    const float* W2  = (const float*)d_in[5];
    const float* b2  = (const float*)d_in[6];
    const float* g2  = (const float*)d_in[7];
    const float* be2 = (const float*)d_in[8];
    float* out = (float*)d_out;

    float* ws   = (float*)d_ws;
    const size_t TSZ = (size_t)NIMG * COUT * HW;  // 8388608 floats = 32 MB
    float* t1   = ws;
    float* t2   = t1 + TSZ;
    float* P1   = t2 + TSZ;                        // [2][COUT][NSLOT]
    float* P2   = P1 + 2 * COUT * NSLOT;
    float* prm1 = P2 + 2 * COUT * NSLOT;           // a[32], b[32]
    float* prm2 = prm1 + 2 * COUT;

    dim3 cgrid(16, NIMG, COUT / OCB);              // (16,16,2)
    peak_conv<CIN,  false, true ><<<cgrid, 256, 0, stream>>>(x,  W1, b1, nullptr, t1, P1);
    bn_stats<<<COUT, 256, 0, stream>>>(P1, g1, be1, prm1);
    peak_conv<COUT, true,  false><<<cgrid, 256, 0, stream>>>(t1, W2, b2, prm1,   t2, P2);
    bn_stats<<<COUT, 256, 0, stream>>>(P2, g2, be2, prm2);
    finalize<<<(BB * COUT * HW) / 256, 256, 0, stream>>>(t2, prm2, out);
}

// Round 4
// 145.423 us; speedup vs baseline: 7.8508x; 7.8508x over previous
//
#include <hip/hip_runtime.h>

using short8 = __attribute__((ext_vector_type(8))) short;
using f32x4  = __attribute__((ext_vector_type(4))) float;

constexpr int BB = 2, FF = 8, CIN = 16, COUT = 32, HH = 128, WW = 128;
constexpr int HW   = HH * WW;         // 16384
constexpr int NIMG = BB * FF;         // 16
constexpr int NTAP = 17;              // 16 ring taps (negated) + 1 center (sum of taps)
constexpr int TIL = 16, HALO = 2, LP = TIL + 2 * HALO;   // 20
constexpr int NPX = LP * LP;          // 400
constexpr int NSLOT = NIMG * 64;      // 1024 partial slots per channel
constexpr int WFSZ = 2 * NTAP * 2 * 64 * 8;  // 34816 ushorts per conv (s,n,oh,lane,j)

// tap offsets in LDS-pixel units: DOFF[n] = dx*LP + dy  (dx = row/h offset, dy = col/w offset)
// ring order: top row dx=-2 dy=-2..2; right col dx=-1..1 dy=2; bottom dx=2 dy=-2..2; left dx=-1..1 dy=-2; n=16 center
__device__ const int DOFF[17] = { -42,-41,-40,-39,-38, -18,2,22, 38,39,40,41,42, -22,-2,18, 0 };

__device__ __forceinline__ float leaky(float v) { return v >= 0.f ? v : 0.01f * v; }
__device__ __forceinline__ unsigned short f2bf(float f) {
    unsigned u = __builtin_bit_cast(unsigned, f);
    u = (u + 0x7FFFu + ((u >> 16) & 1u)) >> 16;
    return (unsigned short)u;
}
__device__ __forceinline__ float bf2f(unsigned short h) {
    unsigned u = ((unsigned)h) << 16;
    return __builtin_bit_cast(float, u);
}

// Scatter weights into A-fragment order for mfma_f32_16x16x32_bf16:
// A[row=oc_local, k=c]: lane l holds rows l&15, k = (l>>4)*8 + j (j=0..7), hi/lo split.
// Wf[((s*17+n)*2+oh)*512 + l*8 + j];  n<16 stores -W[oc][c][n], n==16 stores sum_n W[oc][c][n].
__global__ __launch_bounds__(256)
void prep_weights(const float* __restrict__ W, int ci, unsigned short* __restrict__ Wf)
{
    int idx = blockIdx.x * 256 + threadIdx.x;    // < WFSZ
    int j    = idx & 7;
    int l    = (idx >> 3) & 63;
    int oh   = (idx >> 9) & 1;
    int rest = idx >> 10;                        // s*17 + n
    int n    = rest % 17;
    int s    = rest / 17;
    int oc   = oh * 16 + (l & 15);
    int c    = (l >> 4) * 8 + j;
    float v = 0.f;
    if (c < ci) {
        const float* wp = W + ((size_t)oc * ci + c) * 16;
        if (n < 16) v = -wp[n];
        else { float t = 0.f; for (int q = 0; q < 16; ++q) t += wp[q]; v = t; }
    }
    unsigned short hi = f2bf(v);
    Wf[idx] = s ? f2bf(v - bf2f(hi)) : hi;
}

// One block = one (img, 16x16 spatial tile). 4 waves, each owns 4 pixel-rows (N-groups).
// LDS: [p=ry*20+rx][(s*32 + c) ^ ((p&7)<<3)] ushorts; 128-B line per pixel, XOR-swizzled.
template <int CI, bool PRE, bool XL>
__global__ __launch_bounds__(256)
void peak_conv_mfma(const float* __restrict__ in, const unsigned short* __restrict__ Wf,
                    const float* __restrict__ bk, const float* __restrict__ prm,
                    float* __restrict__ outp, float* __restrict__ P)
{
    __shared__ __align__(16) unsigned short lds[NPX * 64];   // 51200 B
    __shared__ float redS[4][COUT], redQ[4][COUT];

    const int tid    = threadIdx.x;
    const int tileid = blockIdx.x;        // 0..63 (8x8 tiles of 16x16)
    const int img    = blockIdx.y;        // 0..15
    const int tx     = (tileid & 7) * TIL;
    const int ty     = (tileid >> 3) * TIL;
    const int lane   = tid & 63;
    const int wid    = tid >> 6;          // wave id 0..3
    const int rxl    = lane & 15;         // B/D column (pixel x)
    const int cq     = lane >> 4;         // k-quadrant / D-row group

    // ---- stage: fp32 -> bf16 hi/lo into swizzled LDS (zeros for OOB and c>=CI) ----
    for (int e = 0; e < (NPX * 32) / 256; ++e) {   // 50 iters
        int idx = e * 256 + tid;
        int c  = idx / NPX;
        int p  = idx - c * NPX;
        int ry = p / LP, rx = p - ry * LP;
        int gh = ty + ry - HALO, gw = tx + rx - HALO;
        float v = 0.f;
        if (c < CI && (unsigned)gh < (unsigned)HH && (unsigned)gw < (unsigned)WW) {
            const float* src;
            if (XL) src = in + (size_t)(((img >> 3) * CI + c) * FF + (img & 7)) * HW;
            else    src = in + (size_t)(img * CI + c) * HW;
            v = src[gh * WW + gw];
            if (PRE) v = leaky(fmaf(prm[c], v, prm[COUT + c]));  // pad stays 0 AFTER bn+leaky
        }
        unsigned short hi = f2bf(v);
        unsigned short lo = f2bf(v - bf2f(hi));
        int base = p * 64, sw = (p & 7) << 3;
        lds[base + (c ^ sw)]        = hi;
        lds[base + ((32 + c) ^ sw)] = lo;
    }
    __syncthreads();

    // ---- compute: 17 shifted GEMMs, split-bf16 (hi*hi + hi*lo + lo*hi) ----
    f32x4 acc[4][2];
#pragma unroll
    for (int ng = 0; ng < 4; ++ng)
#pragma unroll
        for (int oh = 0; oh < 2; ++oh) acc[ng][oh] = f32x4{0.f, 0.f, 0.f, 0.f};

    int q0[4];
#pragma unroll
    for (int ng = 0; ng < 4; ++ng) q0[ng] = (wid * 4 + ng + HALO) * LP + (rxl + HALO);

    const unsigned short* wl = Wf + lane * 8;

#pragma unroll 1
    for (int n = 0; n < 17; ++n) {
        short8 Ahi0 = *(const short8*)(wl + ((size_t)(( 0 + n) * 2 + 0)) * 512);
        short8 Ahi1 = *(const short8*)(wl + ((size_t)(( 0 + n) * 2 + 1)) * 512);
        short8 Alo0 = *(const short8*)(wl + ((size_t)((17 + n) * 2 + 0)) * 512);
        short8 Alo1 = *(const short8*)(wl + ((size_t)((17 + n) * 2 + 1)) * 512);
        int dof = DOFF[n];
#pragma unroll
        for (int ng = 0; ng < 4; ++ng) {
            int p  = q0[ng] + dof;
            int sw = (p & 7) << 3;
            int b  = p * 64;
            short8 Bhi = *(const short8*)&lds[b + ((cq * 8) ^ sw)];
            short8 Blo = *(const short8*)&lds[b + ((32 + cq * 8) ^ sw)];
            acc[ng][0] = __builtin_amdgcn_mfma_f32_16x16x32_bf16(Ahi0, Bhi, acc[ng][0], 0, 0, 0);
            acc[ng][1] = __builtin_amdgcn_mfma_f32_16x16x32_bf16(Ahi1, Bhi, acc[ng][1], 0, 0, 0);
            acc[ng][0] = __builtin_amdgcn_mfma_f32_16x16x32_bf16(Ahi0, Blo, acc[ng][0], 0, 0, 0);
            acc[ng][1] = __builtin_amdgcn_mfma_f32_16x16x32_bf16(Ahi1, Blo, acc[ng][1], 0, 0, 0);
            acc[ng][0] = __builtin_amdgcn_mfma_f32_16x16x32_bf16(Alo0, Bhi, acc[ng][0], 0, 0, 0);
            acc[ng][1] = __builtin_amdgcn_mfma_f32_16x16x32_bf16(Alo1, Bhi, acc[ng][1], 0, 0, 0);
        }
    }

    // ---- epilogue: bias, store, BN partial sums ----
    float bias_[2][4];
#pragma unroll
    for (int oh = 0; oh < 2; ++oh)
#pragma unroll
        for (int rr = 0; rr < 4; ++rr) bias_[oh][rr] = bk[oh * 16 + cq * 4 + rr];

    float ssum[2][4], ssq[2][4];
#pragma unroll
    for (int oh = 0; oh < 2; ++oh)
#pragma unroll
        for (int rr = 0; rr < 4; ++rr) { ssum[oh][rr] = 0.f; ssq[oh][rr] = 0.f; }

#pragma unroll
    for (int ng = 0; ng < 4; ++ng) {
        int gh = ty + wid * 4 + ng;
        int gw = tx + rxl;
#pragma unroll
        for (int oh = 0; oh < 2; ++oh) {
#pragma unroll
            for (int rr = 0; rr < 4; ++rr) {
                int oc  = oh * 16 + cq * 4 + rr;   // D row = (lane>>4)*4 + reg  [m89-verified]
                float v = acc[ng][oh][rr] + bias_[oh][rr];
                outp[(size_t)(img * COUT + oc) * HW + gh * WW + gw] = v;
                ssum[oh][rr] += v;
                ssq[oh][rr]   = fmaf(v, v, ssq[oh][rr]);
            }
        }
    }

#pragma unroll
    for (int oh = 0; oh < 2; ++oh)
#pragma unroll
        for (int rr = 0; rr < 4; ++rr) {
            float s = ssum[oh][rr], q = ssq[oh][rr];
#pragma unroll
            for (int m = 1; m < 16; m <<= 1) { s += __shfl_xor(s, m); q += __shfl_xor(q, m); }
            if (rxl == 0) {
                redS[wid][oh * 16 + cq * 4 + rr] = s;
                redQ[wid][oh * 16 + cq * 4 + rr] = q;
            }
        }
    __syncthreads();

    const int slot = img * 64 + tileid;
    if (tid < COUT) {
        float s = redS[0][tid] + redS[1][tid] + redS[2][tid] + redS[3][tid];
        P[(size_t)tid * NSLOT + slot] = s;
    } else if (tid < 2 * COUT) {
        int oc = tid - COUT;
        float q = redQ[0][oc] + redQ[1][oc] + redQ[2][oc] + redQ[3][oc];
        P[(size_t)COUT * NSLOT + (size_t)oc * NSLOT + slot] = q;
    }
}

// One block per channel: reduce 1024 partials -> affine a,b
__global__ __launch_bounds__(256)
void bn_stats(const float* __restrict__ P, const float* __restrict__ gamma,
              const float* __restrict__ beta, float* __restrict__ prm)
{
    __shared__ float rs[256], rq[256];
    const int c = blockIdx.x, tid = threadIdx.x;
    const float* Ps = P + (size_t)c * NSLOT;
    const float* Pq = P + (size_t)COUT * NSLOT + (size_t)c * NSLOT;
    rs[tid] = Ps[tid] + Ps[tid + 256] + Ps[tid + 512] + Ps[tid + 768];
    rq[tid] = Pq[tid] + Pq[tid + 256] + Pq[tid + 512] + Pq[tid + 768];
    __syncthreads();
    for (int s = 128; s > 0; s >>= 1) {
        if (tid < s) { rs[tid] += rs[tid + s]; rq[tid] += rq[tid + s]; }
        __syncthreads();
    }
    if (tid == 0) {
        const float n = (float)(NIMG * HW);
        float mu  = rs[0] / n;
        float var = rq[0] / n - mu * mu;
        float a   = gamma[c] * rsqrtf(var + 1e-5f);
        prm[c]        = a;
        prm[COUT + c] = beta[c] - mu * a;
    }
}

// BN2 + leaky + flat-reshape "mean over F":
// out[b][o][p] = (1/8) sum_f leaky(bn2( t2[img=b*8+(o>>2)][c=(o&3)*8+f][p] ))
__global__ __launch_bounds__(256)
void finalize(const float* __restrict__ t2, const float* __restrict__ prm,
              float* __restrict__ outp)
{
    int gid  = blockIdx.x * 256 + threadIdx.x;   // < B*COUT*HW = 1048576
    int p    = gid & (HW - 1);
    int rest = gid >> 14;
    int o    = rest & 31;
    int b    = rest >> 5;
    int img  = b * 8 + (o >> 2);
    int cb   = (o & 3) * 8;
    float s  = 0.f;
#pragma unroll
    for (int f = 0; f < FF; ++f) {
        int c   = cb + f;
        float a = prm[c], bb = prm[COUT + c];
        float v = t2[(size_t)(img * COUT + c) * HW + p];
        v = fmaf(a, v, bb);
        s += (v >= 0.f) ? v : 0.01f * v;
    }
    outp[gid] = 0.125f * s;
}

extern "C" void kernel_launch(void* const* d_in, const int* in_sizes, int n_in,
                              void* d_out, int out_size, void* d_ws, size_t ws_size,
                              hipStream_t stream)
{
    const float* x   = (const float*)d_in[0];
    const float* W1  = (const float*)d_in[1];
    const float* b1  = (const float*)d_in[2];
    const float* g1  = (const float*)d_in[3];
    const float* be1 = (const float*)d_in[4];
    const float* W2  = (const float*)d_in[5];
    const float* b2  = (const float*)d_in[6];
    const float* g2  = (const float*)d_in[7];
    const float* be2 = (const float*)d_in[8];
    float* out = (float*)d_out;

    float* ws = (float*)d_ws;
    const size_t TSZ = (size_t)NIMG * COUT * HW;   // 8388608 floats
    float* t1   = ws;
    float* t2   = t1 + TSZ;
    float* P1   = t2 + TSZ;                        // [2][COUT][1024]  (reused for P2)
    float* prm1 = P1 + 2 * COUT * NSLOT;
    float* prm2 = prm1 + 2 * COUT;
    unsigned short* Wf1 = (unsigned short*)(prm2 + 2 * COUT);
    unsigned short* Wf2 = Wf1 + WFSZ;

    prep_weights<<<WFSZ / 256, 256, 0, stream>>>(W1, CIN,  Wf1);
    prep_weights<<<WFSZ / 256, 256, 0, stream>>>(W2, COUT, Wf2);

    dim3 cg(64, NIMG);
    peak_conv_mfma<CIN,  false, true ><<<cg, 256, 0, stream>>>(x,  Wf1, b1, nullptr, t1, P1);
    bn_stats<<<COUT, 256, 0, stream>>>(P1, g1, be1, prm1);
    peak_conv_mfma<COUT, true,  false><<<cg, 256, 0, stream>>>(t1, Wf2, b2, prm1,   t2, P1);
    bn_stats<<<COUT, 256, 0, stream>>>(P1, g2, be2, prm2);
    finalize<<<(BB * COUT * HW) / 256, 256, 0, stream>>>(t2, prm2, out);
}

// Round 5
// 74.596 us; speedup vs baseline: 15.3049x; 1.9495x over previous
//
#include <hip/hip_runtime.h>

using short8 = __attribute__((ext_vector_type(8))) short;
using f32x4  = __attribute__((ext_vector_type(4))) float;
typedef unsigned short ushort_t;

constexpr int BB = 2, FF = 8, CIN = 16, COUT = 32, HH = 128, WW = 128;
constexpr int HW   = HH * WW;          // 16384
constexpr int NIMG = BB * FF;          // 16
constexpr int TIL = 16, HALO = 2, LP = 20, NPX = 400;
constexpr int NSLOT = 1024;            // 16 img * 64 tiles
constexpr int WFN = 17 * 2 * 512;      // 17408 ushorts per conv (A-frags)

// tap offsets in halo-tile pixel units: DOFF[n] = dx*LP + dy (ring order), n=16 center
__device__ const int DOFF[17] = { -42,-41,-40,-39,-38, -18,2,22, 38,39,40,41,42, -22,-2,18, 0 };

__device__ __forceinline__ float leaky(float v) { return v >= 0.f ? v : 0.01f * v; }
__device__ __forceinline__ ushort_t f2bf(float f) {
    unsigned u = __builtin_bit_cast(unsigned, f);
    u = (u + 0x7FFFu + ((u >> 16) & 1u)) >> 16;
    return (ushort_t)u;
}
__device__ __forceinline__ float bf2f(ushort_t h) {
    unsigned u = ((unsigned)h) << 16;
    return __builtin_bit_cast(float, u);
}

// A-fragments for mfma_f32_16x16x32_bf16, lane l reg j -> row=l&15, k=(l>>4)*8+j.
// dup=1 (conv1): c = k&15  (K packed as [xh(16ch); xl(16ch)] -> A = [wh; wh]).
// dup=0 (conv2): c = k     (K = 32 channels, xh only).
// n<16: -W[oc][c][n];  n==16: sum_n W[oc][c][n].   Wf[(n*2+oh)*512 + l*8 + j]
__global__ __launch_bounds__(256)
void prep_weights(const float* __restrict__ W, int ci, int dup, ushort_t* __restrict__ Wf)
{
    int idx = blockIdx.x * 256 + threadIdx.x;    // < 17408 (68 blocks exact)
    int j  = idx & 7;
    int l  = (idx >> 3) & 63;
    int oh = (idx >> 9) & 1;
    int n  = idx >> 10;                          // 0..16
    int oc = oh * 16 + (l & 15);
    int k  = ((l >> 4) << 3) + j;
    int c  = dup ? (k & 15) : k;
    const float* wp = W + ((size_t)oc * ci + c) * 16;
    float v;
    if (n < 16) v = -wp[n];
    else { v = 0.f; for (int q = 0; q < 16; ++q) v += wp[q]; }
    Wf[idx] = f2bf(v);
}

// One block = (img, 16x16 spatial tile); 4 waves, wave owns 4 pixel rows.
// LDS: per pixel p, 4 slots x 8 ushorts (16 B), slot index XOR-swizzled by
// swz(p) = (p&3)^((p>>2)&3).  MODE 0: conv1 from plane-major x, slots =
// [xh c0-7][xh c8-15][xl c0-7][xl c8-15].  MODE 1: conv2 from pixel-major t1,
// slots = [xh c0-7][c8-15][c16-23][c24-31] (BN1 affine + leaky applied, pad=0).
template <int MODE>
__global__ __launch_bounds__(256)
void peak_conv_mfma(const float* __restrict__ in, const ushort_t* __restrict__ Wf,
                    const float* __restrict__ bk, const float* __restrict__ prm,
                    float* __restrict__ outp, float* __restrict__ P)
{
    __shared__ __align__(16) ushort_t lds[NPX * 32];   // 25600 B
    __shared__ float redS[4][COUT], redQ[4][COUT];

    const int tid    = threadIdx.x;
    const int tileid = blockIdx.x;        // 0..63
    const int img    = blockIdx.y;        // 0..15
    const int tx     = (tileid & 7) * TIL;
    const int ty     = (tileid >> 3) * TIL;
    const int lane   = tid & 63;
    const int wid    = tid >> 6;
    const int rxl    = lane & 15;         // B/D column (pixel x)
    const int cq     = lane >> 4;         // k-quadrant / D-row group

    // ---- staging ----
    if (MODE == 0) {
        // 800 tasks = 2 channel-octets x 400 px; 8 coalesced scalar loads each
#pragma unroll
        for (int e = 0; e < 4; ++e) {
            int task = e * 256 + tid;
            if (task < 800) {
                int h  = task >= 400 ? 1 : 0;
                int p  = task - h * 400;
                int ry = p / LP, rx = p - ry * LP;
                int gh = ty + ry - HALO, gw = tx + rx - HALO;
                bool ok = (unsigned)gh < (unsigned)HH && (unsigned)gw < (unsigned)WW;
                int ghc = min(max(gh, 0), HH - 1), gwc = min(max(gw, 0), WW - 1);
                const float* base = in + (((size_t)(img >> 3) * CIN + 8 * h) * FF + (img & 7)) * HW
                                       + ghc * WW + gwc;
                short8 hi8, lo8;
#pragma unroll
                for (int cc = 0; cc < 8; ++cc) {
                    float v = base[(size_t)cc * FF * HW];
                    v = ok ? v : 0.f;
                    ushort_t hi = f2bf(v);
                    hi8[cc] = (short)hi;
                    lo8[cc] = (short)f2bf(v - bf2f(hi));
                }
                int swz = (p & 3) ^ ((p >> 2) & 3);
                *(short8*)&lds[p * 32 + 8 * (h ^ swz)]       = hi8;
                *(short8*)&lds[p * 32 + 8 * ((2 + h) ^ swz)] = lo8;
            }
        }
    } else {
        // 1600 tasks = 4 channel-octets x 400 px; 2 float4 loads each (pixel-major t1)
#pragma unroll
        for (int e = 0; e < 7; ++e) {
            int task = e * 256 + tid;
            if (task < 1600) {
                int g  = task & 3, p = task >> 2;
                int ry = p / LP, rx = p - ry * LP;
                int gh = ty + ry - HALO, gw = tx + rx - HALO;
                bool ok = (unsigned)gh < (unsigned)HH && (unsigned)gw < (unsigned)WW;
                int ghc = min(max(gh, 0), HH - 1), gwc = min(max(gw, 0), WW - 1);
                const float* px = in + ((size_t)img * HW + ghc * WW + gwc) * 32 + 8 * g;
                f32x4 v0 = *(const f32x4*)px;
                f32x4 v1 = *(const f32x4*)(px + 4);
                short8 hv;
#pragma unroll
                for (int jj = 0; jj < 4; ++jj) {
                    int c0 = 8 * g + jj, c1 = c0 + 4;
                    float va = leaky(fmaf(prm[c0], v0[jj], prm[COUT + c0]));
                    float vb = leaky(fmaf(prm[c1], v1[jj], prm[COUT + c1]));
                    hv[jj]     = (short)f2bf(ok ? va : 0.f);
                    hv[4 + jj] = (short)f2bf(ok ? vb : 0.f);
                }
                int swz = (p & 3) ^ ((p >> 2) & 3);
                *(short8*)&lds[p * 32 + 8 * (g ^ swz)] = hv;
            }
        }
    }
    __syncthreads();

    // ---- compute: 17 shifted GEMMs, 2 MFMA each (oc halves) ----
    f32x4 acc[4][2];
#pragma unroll
    for (int ng = 0; ng < 4; ++ng)
#pragma unroll
        for (int oh = 0; oh < 2; ++oh) acc[ng][oh] = f32x4{0.f, 0.f, 0.f, 0.f};

    int q0[4];
#pragma unroll
    for (int ng = 0; ng < 4; ++ng) q0[ng] = (wid * 4 + ng + HALO) * LP + (rxl + HALO);

    const ushort_t* wl = Wf + (size_t)lane * 8;

#pragma unroll 1
    for (int n = 0; n < 17; ++n) {
        short8 A0 = *(const short8*)(wl + (size_t)(n * 2 + 0) * 512);
        short8 A1 = *(const short8*)(wl + (size_t)(n * 2 + 1) * 512);
        int dof = DOFF[n];
#pragma unroll
        for (int ng = 0; ng < 4; ++ng) {
            int p   = q0[ng] + dof;
            int swz = (p & 3) ^ ((p >> 2) & 3);
            short8 Bv = *(const short8*)&lds[p * 32 + 8 * (cq ^ swz)];
            acc[ng][0] = __builtin_amdgcn_mfma_f32_16x16x32_bf16(A0, Bv, acc[ng][0], 0, 0, 0);
            acc[ng][1] = __builtin_amdgcn_mfma_f32_16x16x32_bf16(A1, Bv, acc[ng][1], 0, 0, 0);
        }
    }

    // ---- epilogue: bias, pixel-major store, BN partials ----
    float bias_[2][4];
#pragma unroll
    for (int oh = 0; oh < 2; ++oh)
#pragma unroll
        for (int rr = 0; rr < 4; ++rr) bias_[oh][rr] = bk[oh * 16 + cq * 4 + rr];

    float ssum[2][4], ssq[2][4];
#pragma unroll
    for (int oh = 0; oh < 2; ++oh)
#pragma unroll
        for (int rr = 0; rr < 4; ++rr) { ssum[oh][rr] = 0.f; ssq[oh][rr] = 0.f; }

#pragma unroll
    for (int ng = 0; ng < 4; ++ng) {
        int gh = ty + wid * 4 + ng, gw = tx + rxl;
        size_t pxb = ((size_t)img * HW + gh * WW + gw) * 32;
#pragma unroll
        for (int oh = 0; oh < 2; ++oh) {
            f32x4 vv;
#pragma unroll
            for (int rr = 0; rr < 4; ++rr) {
                float v = acc[ng][oh][rr] + bias_[oh][rr];
                vv[rr] = v;
                ssum[oh][rr] += v;
                ssq[oh][rr]   = fmaf(v, v, ssq[oh][rr]);
            }
            *(f32x4*)&outp[pxb + oh * 16 + cq * 4] = vv;
        }
    }

#pragma unroll
    for (int oh = 0; oh < 2; ++oh)
#pragma unroll
        for (int rr = 0; rr < 4; ++rr) {
            float s = ssum[oh][rr], q = ssq[oh][rr];
#pragma unroll
            for (int m = 1; m < 16; m <<= 1) { s += __shfl_xor(s, m); q += __shfl_xor(q, m); }
            if (rxl == 0) {
                redS[wid][oh * 16 + cq * 4 + rr] = s;
                redQ[wid][oh * 16 + cq * 4 + rr] = q;
            }
        }
    __syncthreads();

    const int slot = img * 64 + tileid;
    if (tid < COUT) {
        float s = redS[0][tid] + redS[1][tid] + redS[2][tid] + redS[3][tid];
        P[(size_t)tid * NSLOT + slot] = s;
    } else if (tid < 2 * COUT) {
        int oc = tid - COUT;
        float q = redQ[0][oc] + redQ[1][oc] + redQ[2][oc] + redQ[3][oc];
        P[(size_t)COUT * NSLOT + (size_t)oc * NSLOT + slot] = q;
    }
}

// One block per channel: reduce 1024 partials -> affine a,b
__global__ __launch_bounds__(256)
void bn_stats(const float* __restrict__ P, const float* __restrict__ gamma,
              const float* __restrict__ beta, float* __restrict__ prm)
{
    __shared__ float rs[256], rq[256];
    const int c = blockIdx.x, tid = threadIdx.x;
    const float* Ps = P + (size_t)c * NSLOT;
    const float* Pq = P + (size_t)COUT * NSLOT + (size_t)c * NSLOT;
    rs[tid] = Ps[tid] + Ps[tid + 256] + Ps[tid + 512] + Ps[tid + 768];
    rq[tid] = Pq[tid] + Pq[tid + 256] + Pq[tid + 512] + Pq[tid + 768];
    __syncthreads();
    for (int s = 128; s > 0; s >>= 1) {
        if (tid < s) { rs[tid] += rs[tid + s]; rq[tid] += rq[tid + s]; }
        __syncthreads();
    }
    if (tid == 0) {
        const float n = (float)(NIMG * HW);
        float mu  = rs[0] / n;
        float var = rq[0] / n - mu * mu;
        float a   = gamma[c] * rsqrtf(var + 1e-5f);
        prm[c]        = a;
        prm[COUT + c] = beta[c] - mu * a;
    }
}

// BN2 + leaky + flat-reshape "mean over F" from pixel-major t2:
// out[b][o][p] = (1/8) sum_j leaky(bn2( t2px[img=b*8+(o>>2)][p][c=(o&3)*8+j] ))
__global__ __launch_bounds__(256)
void finalize(const float* __restrict__ t2, const float* __restrict__ prm,
              float* __restrict__ outp)
{
    int gid  = blockIdx.x * 256 + threadIdx.x;   // < 1048576
    int p    = gid & (HW - 1);
    int rest = gid >> 14;
    int o    = rest & 31;
    int b    = rest >> 5;
    int img  = b * 8 + (o >> 2);
    int cb   = (o & 3) * 8;
    const float* px = t2 + ((size_t)img * HW + p) * 32 + cb;
    f32x4 v0 = *(const f32x4*)px;
    f32x4 v1 = *(const f32x4*)(px + 4);
    float s = 0.f;
#pragma unroll
    for (int j = 0; j < 4; ++j) {
        int c0 = cb + j, c1 = c0 + 4;
        s += leaky(fmaf(prm[c0], v0[j], prm[COUT + c0]));
        s += leaky(fmaf(prm[c1], v1[j], prm[COUT + c1]));
    }
    outp[gid] = 0.125f * s;
}

extern "C" void kernel_launch(void* const* d_in, const int* in_sizes, int n_in,
                              void* d_out, int out_size, void* d_ws, size_t ws_size,
                              hipStream_t stream)
{
    const float* x   = (const float*)d_in[0];
    const float* W1  = (const float*)d_in[1];
    const float* b1  = (const float*)d_in[2];
    const float* g1  = (const float*)d_in[3];
    const float* be1 = (const float*)d_in[4];
    const float* W2  = (const float*)d_in[5];
    const float* b2  = (const float*)d_in[6];
    const float* g2  = (const float*)d_in[7];
    const float* be2 = (const float*)d_in[8];
    float* out = (float*)d_out;

    float* ws = (float*)d_ws;
    const size_t TSZ = (size_t)NIMG * HW * 32;     // 8388608 floats (pixel-major)
    float* t1   = ws;
    float* t2   = t1 + TSZ;
    float* P    = t2 + TSZ;                        // [2][COUT][1024]
    float* prm1 = P + 2 * COUT * NSLOT;
    float* prm2 = prm1 + 2 * COUT;
    ushort_t* Wf1 = (ushort_t*)(prm2 + 2 * COUT);
    ushort_t* Wf2 = Wf1 + WFN;

    prep_weights<<<WFN / 256, 256, 0, stream>>>(W1, CIN,  1, Wf1);
    prep_weights<<<WFN / 256, 256, 0, stream>>>(W2, COUT, 0, Wf2);

    dim3 cg(64, NIMG);
    peak_conv_mfma<0><<<cg, 256, 0, stream>>>(x,  Wf1, b1, nullptr, t1, P);
    bn_stats<<<COUT, 256, 0, stream>>>(P, g1, be1, prm1);
    peak_conv_mfma<1><<<cg, 256, 0, stream>>>(t1, Wf2, b2, prm1,   t2, P);
    bn_stats<<<COUT, 256, 0, stream>>>(P, g2, be2, prm2);
    finalize<<<(BB * COUT * HW) / 256, 256, 0, stream>>>(t2, prm2, out);
}

// Round 7
// 64.183 us; speedup vs baseline: 17.7879x; 1.1622x over previous
//
#include <hip/hip_runtime.h>

using short8 = __attribute__((ext_vector_type(8))) short;
using sh4    = __attribute__((ext_vector_type(4))) short;
using f32x4  = __attribute__((ext_vector_type(4))) float;
typedef unsigned short ushort_t;

constexpr int BB = 2, FF = 8, CIN = 16, COUT = 32, HH = 128, WW = 128;
constexpr int HW   = HH * WW;          // 16384
constexpr int NIMG = BB * FF;          // 16
constexpr int TIL = 16, HALO = 2, LP = 20, NPX = 400;
constexpr int NSLOT = 1024;            // 16 img * 64 tiles
constexpr int WFN = 17 * 2 * 512;      // 17408 ushorts per conv (A-frags)

// tap offsets in halo-tile pixel units: DOFF[n] = dx*LP + dy (ring order), n=16 center
__device__ const int DOFF[17] = { -42,-41,-40,-39,-38, -18,2,22, 38,39,40,41,42, -22,-2,18, 0 };

__device__ __forceinline__ float leaky(float v) { return v >= 0.f ? v : 0.01f * v; }
__device__ __forceinline__ ushort_t f2bf(float f) {
    unsigned u = __builtin_bit_cast(unsigned, f);
    u = (u + 0x7FFFu + ((u >> 16) & 1u)) >> 16;
    return (ushort_t)u;
}
__device__ __forceinline__ float bf2f(ushort_t h) {
    unsigned u = ((unsigned)h) << 16;
    return __builtin_bit_cast(float, u);
}

// A-fragments for mfma_f32_16x16x32_bf16, lane l reg j -> row=l&15, k=(l>>4)*8+j.
// which=0 (conv1): dup, c = k&15 (K packed [xh(16ch); xl(16ch)] -> A = [wh; wh]).
// which=1 (conv2): c = k (K = 32 channels, xh only).
// n<16: -W[oc][c][n];  n==16: sum_n W[oc][c][n].   Wf[(n*2+oh)*512 + l*8 + j]
__global__ __launch_bounds__(256)
void prep_weights(const float* __restrict__ W1, const float* __restrict__ W2,
                  ushort_t* __restrict__ Wf1, ushort_t* __restrict__ Wf2)
{
    int which = blockIdx.y;
    const float* W = which ? W2 : W1;
    ushort_t* Wf   = which ? Wf2 : Wf1;
    int ci         = which ? COUT : CIN;

    int idx = blockIdx.x * 256 + threadIdx.x;    // < 17408 (68 blocks exact)
    int j  = idx & 7;
    int l  = (idx >> 3) & 63;
    int oh = (idx >> 9) & 1;
    int n  = idx >> 10;                          // 0..16
    int oc = oh * 16 + (l & 15);
    int k  = ((l >> 4) << 3) + j;
    int c  = which ? k : (k & 15);
    const float* wp = W + ((size_t)oc * ci + c) * 16;
    float v;
    if (n < 16) v = -wp[n];
    else { v = 0.f; for (int q = 0; q < 16; ++q) v += wp[q]; }
    Wf[idx] = f2bf(v);
}

// One block = (img, 16x16 spatial tile); 4 waves, wave owns 4 pixel rows.
// LDS: per pixel p, 4 slots x 8 ushorts (16 B), slot XOR-swizzled by
// swz(p) = (p&3)^((p>>2)&3).  MODE 0: conv1 from plane-major fp32 x, slots =
// [xh c0-7][xh c8-15][xl c0-7][xl c8-15].  MODE 1: conv2 from pixel-major bf16
// t1, slots = [c0-7][c8-15][c16-23][c24-31] (BN1 affine + leaky, pad=0).
template <int MODE>
__global__ __launch_bounds__(256)
void peak_conv_mfma(const float* __restrict__ inf, const ushort_t* __restrict__ inh,
                    const ushort_t* __restrict__ Wf,
                    const float* __restrict__ bk, const float* __restrict__ prm,
                    ushort_t* __restrict__ outp, float* __restrict__ P)
{
    __shared__ __align__(16) ushort_t lds[NPX * 32];   // 25600 B
    __shared__ float redS[4][COUT], redQ[4][COUT];

    const int tid    = threadIdx.x;
    const int tileid = blockIdx.x;        // 0..63
    const int img    = blockIdx.y;        // 0..15
    const int tx     = (tileid & 7) * TIL;
    const int ty     = (tileid >> 3) * TIL;
    const int lane   = tid & 63;
    const int wid    = tid >> 6;
    const int rxl    = lane & 15;         // B/D column (pixel x)
    const int cq     = lane >> 4;         // k-quadrant / D-row group

    // ---- staging ----
    if (MODE == 0) {
        // 800 tasks = 2 channel-octets x 400 px; 8 coalesced scalar fp32 loads each
#pragma unroll
        for (int e = 0; e < 4; ++e) {
            int task = e * 256 + tid;
            if (task < 800) {
                int h  = task >= 400 ? 1 : 0;
                int p  = task - h * 400;
                int ry = p / LP, rx = p - ry * LP;
                int gh = ty + ry - HALO, gw = tx + rx - HALO;
                bool ok = (unsigned)gh < (unsigned)HH && (unsigned)gw < (unsigned)WW;
                int ghc = min(max(gh, 0), HH - 1), gwc = min(max(gw, 0), WW - 1);
                const float* base = inf + (((size_t)(img >> 3) * CIN + 8 * h) * FF + (img & 7)) * HW
                                       + ghc * WW + gwc;
                short8 hi8, lo8;
#pragma unroll
                for (int cc = 0; cc < 8; ++cc) {
                    float v = base[(size_t)cc * FF * HW];
                    v = ok ? v : 0.f;
                    ushort_t hi = f2bf(v);
                    hi8[cc] = (short)hi;
                    lo8[cc] = (short)f2bf(v - bf2f(hi));
                }
                int swz = (p & 3) ^ ((p >> 2) & 3);
                *(short8*)&lds[p * 32 + 8 * (h ^ swz)]       = hi8;
                *(short8*)&lds[p * 32 + 8 * ((2 + h) ^ swz)] = lo8;
            }
        }
    } else {
        // 1600 tasks = 4 channel-octets x 400 px; one short8 (16 B) load each
#pragma unroll
        for (int e = 0; e < 7; ++e) {
            int task = e * 256 + tid;
            if (task < 1600) {
                int g  = task & 3, p = task >> 2;
                int ry = p / LP, rx = p - ry * LP;
                int gh = ty + ry - HALO, gw = tx + rx - HALO;
                bool ok = (unsigned)gh < (unsigned)HH && (unsigned)gw < (unsigned)WW;
                int ghc = min(max(gh, 0), HH - 1), gwc = min(max(gw, 0), WW - 1);
                const ushort_t* px = inh + ((size_t)img * HW + ghc * WW + gwc) * 32 + 8 * g;
                short8 raw = *(const short8*)px;
                short8 hv;
#pragma unroll
                for (int jj = 0; jj < 8; ++jj) {
                    int c = 8 * g + jj;
                    float v = bf2f((ushort_t)raw[jj]);
                    v = leaky(fmaf(prm[c], v, prm[COUT + c]));
                    hv[jj] = (short)f2bf(ok ? v : 0.f);
                }
                int swz = (p & 3) ^ ((p >> 2) & 3);
                *(short8*)&lds[p * 32 + 8 * (g ^ swz)] = hv;
            }
        }
    }
    __syncthreads();

    // ---- compute: 17 shifted GEMMs, 2 MFMA each (oc halves) ----
    f32x4 acc[4][2];
#pragma unroll
    for (int ng = 0; ng < 4; ++ng)
#pragma unroll
        for (int oh = 0; oh < 2; ++oh) acc[ng][oh] = f32x4{0.f, 0.f, 0.f, 0.f};

    int q0[4];
#pragma unroll
    for (int ng = 0; ng < 4; ++ng) q0[ng] = (wid * 4 + ng + HALO) * LP + (rxl + HALO);

    const ushort_t* wl = Wf + (size_t)lane * 8;

#pragma unroll 1
    for (int n = 0; n < 17; ++n) {
        short8 A0 = *(const short8*)(wl + (size_t)(n * 2 + 0) * 512);
        short8 A1 = *(const short8*)(wl + (size_t)(n * 2 + 1) * 512);
        int dof = DOFF[n];
#pragma unroll
        for (int ng = 0; ng < 4; ++ng) {
            int p   = q0[ng] + dof;
            int swz = (p & 3) ^ ((p >> 2) & 3);
            short8 Bv = *(const short8*)&lds[p * 32 + 8 * (cq ^ swz)];
            acc[ng][0] = __builtin_amdgcn_mfma_f32_16x16x32_bf16(A0, Bv, acc[ng][0], 0, 0, 0);
            acc[ng][1] = __builtin_amdgcn_mfma_f32_16x16x32_bf16(A1, Bv, acc[ng][1], 0, 0, 0);
        }
    }

    // ---- epilogue: bias, bf16 pixel-major store, BN partials (fp32-exact) ----
    float bias_[2][4];
#pragma unroll
    for (int oh = 0; oh < 2; ++oh)
#pragma unroll
        for (int rr = 0; rr < 4; ++rr) bias_[oh][rr] = bk[oh * 16 + cq * 4 + rr];

    float ssum[2][4], ssq[2][4];
#pragma unroll
    for (int oh = 0; oh < 2; ++oh)
#pragma unroll
        for (int rr = 0; rr < 4; ++rr) { ssum[oh][rr] = 0.f; ssq[oh][rr] = 0.f; }

#pragma unroll
    for (int ng = 0; ng < 4; ++ng) {
        int gh = ty + wid * 4 + ng, gw = tx + rxl;
        size_t pxb = ((size_t)img * HW + gh * WW + gw) * 32;
#pragma unroll
        for (int oh = 0; oh < 2; ++oh) {
            sh4 sv;
#pragma unroll
            for (int rr = 0; rr < 4; ++rr) {
                float v = acc[ng][oh][rr] + bias_[oh][rr];
                sv[rr] = (short)f2bf(v);
                ssum[oh][rr] += v;
                ssq[oh][rr]   = fmaf(v, v, ssq[oh][rr]);
            }
            *(sh4*)&outp[pxb + oh * 16 + cq * 4] = sv;
        }
    }

#pragma unroll
    for (int oh = 0; oh < 2; ++oh)
#pragma unroll
        for (int rr = 0; rr < 4; ++rr) {
            float s = ssum[oh][rr], q = ssq[oh][rr];
#pragma unroll
            for (int m = 1; m < 16; m <<= 1) { s += __shfl_xor(s, m); q += __shfl_xor(q, m); }
            if (rxl == 0) {
                redS[wid][oh * 16 + cq * 4 + rr] = s;
                redQ[wid][oh * 16 + cq * 4 + rr] = q;
            }
        }
    __syncthreads();

    const int slot = img * 64 + tileid;
    if (tid < COUT) {
        float s = redS[0][tid] + redS[1][tid] + redS[2][tid] + redS[3][tid];
        P[(size_t)tid * NSLOT + slot] = s;
    } else if (tid < 2 * COUT) {
        int oc = tid - COUT;
        float q = redQ[0][oc] + redQ[1][oc] + redQ[2][oc] + redQ[3][oc];
        P[(size_t)COUT * NSLOT + (size_t)oc * NSLOT + slot] = q;
    }
}

// One block per channel: reduce 1024 partials -> affine a,b
__global__ __launch_bounds__(256)
void bn_stats(const float* __restrict__ P, const float* __restrict__ gamma,
              const float* __restrict__ beta, float* __restrict__ prm)
{
    __shared__ float rs[256], rq[256];
    const int c = blockIdx.x, tid = threadIdx.x;
    const float* Ps = P + (size_t)c * NSLOT;
    const float* Pq = P + (size_t)COUT * NSLOT + (size_t)c * NSLOT;
    rs[tid] = Ps[tid] + Ps[tid + 256] + Ps[tid + 512] + Ps[tid + 768];
    rq[tid] = Pq[tid] + Pq[tid + 256] + Pq[tid + 512] + Pq[tid + 768];
    __syncthreads();
    for (int s = 128; s > 0; s >>= 1) {
        if (tid < s) { rs[tid] += rs[tid + s]; rq[tid] += rq[tid + s]; }
        __syncthreads();
    }
    if (tid == 0) {
        const float n = (float)(NIMG * HW);
        float mu  = rs[0] / n;
        float var = rq[0] / n - mu * mu;
        float a   = gamma[c] * rsqrtf(var + 1e-5f);
        prm[c]        = a;
        prm[COUT + c] = beta[c] - mu * a;
    }
}

// BN2 + leaky + flat-reshape "mean over F" from pixel-major bf16 t2:
// out[b][o][p] = (1/8) sum_j leaky(bn2( t2px[img=b*8+(o>>2)][p][c=(o&3)*8+j] ))
__global__ __launch_bounds__(256)
void finalize(const ushort_t* __restrict__ t2, const float* __restrict__ prm,
              float* __restrict__ outp)
{
    int gid  = blockIdx.x * 256 + threadIdx.x;   // < 1048576
    int p    = gid & (HW - 1);
    int rest = gid >> 14;
    int o    = rest & 31;
    int b    = rest >> 5;
    int img  = b * 8 + (o >> 2);
    int cb   = (o & 3) * 8;
    const ushort_t* px = t2 + ((size_t)img * HW + p) * 32 + cb;
    short8 raw = *(const short8*)px;
    float s = 0.f;
#pragma unroll
    for (int j = 0; j < 8; ++j) {
        int c = cb + j;
        float v = bf2f((ushort_t)raw[j]);
        s += leaky(fmaf(prm[c], v, prm[COUT + c]));
    }
    outp[gid] = 0.125f * s;
}

extern "C" void kernel_launch(void* const* d_in, const int* in_sizes, int n_in,
                              void* d_out, int out_size, void* d_ws, size_t ws_size,
                              hipStream_t stream)
{
    const float* x   = (const float*)d_in[0];
    const float* W1  = (const float*)d_in[1];
    const float* b1  = (const float*)d_in[2];
    const float* g1  = (const float*)d_in[3];
    const float* be1 = (const float*)d_in[4];
    const float* W2  = (const float*)d_in[5];
    const float* b2  = (const float*)d_in[6];
    const float* g2  = (const float*)d_in[7];
    const float* be2 = (const float*)d_in[8];
    float* out = (float*)d_out;

    const size_t TSZH = (size_t)NIMG * HW * 32;    // 8388608 bf16 elems (16 MB)
    ushort_t* t1   = (ushort_t*)d_ws;
    ushort_t* t2   = t1 + TSZH;
    float*    P    = (float*)(t2 + TSZH);          // [2][COUT][1024]
    float*    prm1 = P + 2 * COUT * NSLOT;
    float*    prm2 = prm1 + 2 * COUT;
    ushort_t* Wf1  = (ushort_t*)(prm2 + 2 * COUT);
    ushort_t* Wf2  = Wf1 + WFN;

    dim3 pg(WFN / 256, 2);
    prep_weights<<<pg, 256, 0, stream>>>(W1, W2, Wf1, Wf2);

    dim3 cg(64, NIMG);
    peak_conv_mfma<0><<<cg, 256, 0, stream>>>(x,  nullptr, Wf1, b1, nullptr, t1, P);
    bn_stats<<<COUT, 256, 0, stream>>>(P, g1, be1, prm1);
    peak_conv_mfma<1><<<cg, 256, 0, stream>>>(nullptr, t1, Wf2, b2, prm1,   t2, P);
    bn_stats<<<COUT, 256, 0, stream>>>(P, g2, be2, prm2);
    finalize<<<(BB * COUT * HW) / 256, 256, 0, stream>>>(t2, prm2, out);
}